// Round 1
// baseline (328.426 us; speedup 1.0000x reference)
//
#include <hip/hip_runtime.h>

// CompetitiveLayer: fixed-point iterations of
//   BF = BT / (1 + K^T @ AF);  AF = AT / (1 + K @ BF);  K = k*k, BT = bt*bt
// then C = AF[:,None] * K * BF[None,:].  N = 4096.
//
// Persistent kernel, 256 blocks (1/CU forced by ~150 KB LDS), each holds a
// 256x256 bf16 slab of K in LDS.
// R7 changes (attacking sync latency: 8.2 us/iter measured, only ~1 us is VALU):
//  (1) Wave-specialized sync, 8 -> 4 full barriers/iter. Wave 0 alone
//      reduces scratch (ds_read_b64), publishes the slice as coalesced 8B
//      agent stores, drains with a WAVE-LOCAL s_waitcnt vmcnt(0), stores the
//      flag. Waves 1-4 poll the 16-flag line directly (flags replicated
//      across 64 lanes, __all), compiler fence, then gather+BF/AF with no
//      intervening block barrier. Protocol (monotone tags, parity slots)
//      identical to R6. WAR chain preserved: reader's data loads at it are
//      consumed before it passes B2/B4, which precede its flag at it+1,
//      which gates writer slot reuse at it+2.
//  (2) NITER 24->20: absmax 3.814697e-06 == 2^-18 is the bf16 floor and was
//      bit-identical at 64/48/32 => contraction q <~ 0.52; residual at 20
//      iters ~1.4e-3 rel -> dC ~4e-7, 10x under floor. Revert if absmax moves.

#define NSIDE 4096
#define NBLK  256     // 16 x 16 block grid
#define TPB   1024
#define SR    256
#define SC    256
#define NITER 20
#define FANIN 16

typedef float f32x2 __attribute__((ext_vector_type(2)));

__device__ __forceinline__ unsigned short f32_to_bf16(float f) {
  unsigned u = __float_as_uint(f);
  u += 0x7FFFu + ((u >> 16) & 1u);   // round-to-nearest-even
  return (unsigned short)(u >> 16);
}
__device__ __forceinline__ float bfLO(unsigned q) { return __uint_as_float(q << 16); }
__device__ __forceinline__ float bfHI(unsigned q) { return __uint_as_float(q & 0xFFFF0000u); }

__device__ __forceinline__ float ld_agent_f(const float* p) {
  return __hip_atomic_load(p, __ATOMIC_RELAXED, __HIP_MEMORY_SCOPE_AGENT);
}
__device__ __forceinline__ void st_agent_u(unsigned* p, unsigned v) {
  __hip_atomic_store(p, v, __ATOMIC_RELAXED, __HIP_MEMORY_SCOPE_AGENT);
}
__device__ __forceinline__ unsigned ld_agent_u(const unsigned* p) {
  return __hip_atomic_load(p, __ATOMIC_RELAXED, __HIP_MEMORY_SCOPE_AGENT);
}
__device__ __forceinline__ void st_agent_u64(unsigned long long* p, unsigned long long v) {
  __hip_atomic_store(p, v, __ATOMIC_RELAXED, __HIP_MEMORY_SCOPE_AGENT);
}
__device__ __forceinline__ unsigned long long pack2(f32x2 v) {
  union { f32x2 f; unsigned long long u; } cv; cv.f = v; return cv.u;
}
__device__ __forceinline__ void wait_vm0() {
  asm volatile("s_waitcnt vmcnt(0)" ::: "memory");
}

__global__ void ws_init_kernel(unsigned* flags) {
  const int i = threadIdx.x;
  if (i < 2 * FANIN * FANIN) flags[i] = 0u;   // 512 u32: ColFlag + RowFlag
}

__global__ void __launch_bounds__(TPB) competitive_kernel(
    const float* __restrict__ AT, const float* __restrict__ kmat,
    const float* __restrict__ bt, float* __restrict__ C,
    unsigned* __restrict__ ColFlag, unsigned* __restrict__ RowFlag,
    float* __restrict__ ColData, float* __restrict__ RowData) {

  __shared__ unsigned short slab[SR * SC];   // 128 KB bf16(K), row-major
  __shared__ float scratch[16 * SC];         // col-pass wave partials
  __shared__ float rowsum[SR];               // row-pass totals
  __shared__ float AFs[SR];
  __shared__ float BFs[SC];
  __shared__ float ATs[SR];
  __shared__ float BTs[SC];

  const int t   = threadIdx.x;
  const int bid = blockIdx.x;
  const int br  = bid >> 4;
  const int bc  = bid & 15;
  const int R0  = br * SR;
  const int C0  = bc * SC;

  // ---------------- stage slab: K = k*k as bf16 ----------------
  {
    const int c4 = t & 63;
    const int rh = t >> 6;
#pragma unroll
    for (int s = 0; s < 16; ++s) {
      const int r = s * 16 + rh;
      const float4 v = reinterpret_cast<const float4*>(kmat + (size_t)(R0 + r) * NSIDE + C0)[c4];
      ushort4 u;
      u.x = f32_to_bf16(v.x * v.x);
      u.y = f32_to_bf16(v.y * v.y);
      u.z = f32_to_bf16(v.z * v.z);
      u.w = f32_to_bf16(v.w * v.w);
      *reinterpret_cast<ushort4*>(&slab[r * SC + c4 * 4]) = u;
    }
  }
  if (t < SR) { const float a = AT[R0 + t]; ATs[t] = a; AFs[t] = a; }   // AF_0 = AT
  if (t < SC) { const float b = bt[C0 + t]; BTs[t] = b * b; }
  __syncthreads();

  const int c    = t & 31;   // column-group: cols c*8 .. c*8+7
  const int rg   = t >> 5;   // 0..31
  const int w    = t >> 6;   // wave id 0..15
  const int lane = t & 63;

  for (int it = 0; it < NITER; ++it) {
    const unsigned tag = (unsigned)(it + 1);
    float* CD = ColData + (size_t)(it & 1) * FANIN * NSIDE;   // [16][4096] this parity
    float* RD = RowData + (size_t)(it & 1) * FANIN * NSIDE;

    // ============ column pass: partial_j = sum_i K_ij * AF_i ============
    {
      float a0 = 0.f, a1 = 0.f, a2 = 0.f, a3 = 0.f, a4 = 0.f, a5 = 0.f, a6 = 0.f, a7 = 0.f;
#pragma unroll
      for (int s = 0; s < 8; ++s) {
        const int row = rg + s * 32;
        const float af = AFs[row];
        const uint4 q = *reinterpret_cast<const uint4*>(&slab[row * SC + c * 8]);
        a0 += bfLO(q.x) * af;  a1 += bfHI(q.x) * af;
        a2 += bfLO(q.y) * af;  a3 += bfHI(q.y) * af;
        a4 += bfLO(q.z) * af;  a5 += bfHI(q.z) * af;
        a6 += bfLO(q.w) * af;  a7 += bfHI(q.w) * af;
      }
      a0 += __shfl_down(a0, 32); a1 += __shfl_down(a1, 32);
      a2 += __shfl_down(a2, 32); a3 += __shfl_down(a3, 32);
      a4 += __shfl_down(a4, 32); a5 += __shfl_down(a5, 32);
      a6 += __shfl_down(a6, 32); a7 += __shfl_down(a7, 32);
      if ((t & 63) < 32) {
        float4* dst = reinterpret_cast<float4*>(&scratch[w * SC + c * 8]);
        dst[0] = make_float4(a0, a1, a2, a3);
        dst[1] = make_float4(a4, a5, a6, a7);
      }
    }
    __syncthreads();                                          // B1: scratch ready

    if (w == 0) {
      // wave 0: reduce 16 wave-partials, publish slice + flag (wave-local drain)
      f32x2 s0 = {0.f, 0.f}, s1 = {0.f, 0.f};
#pragma unroll
      for (int ww = 0; ww < 16; ++ww) {
        s0 += *reinterpret_cast<const f32x2*>(&scratch[ww * SC + 2 * lane]);
        s1 += *reinterpret_cast<const f32x2*>(&scratch[ww * SC + 128 + 2 * lane]);
      }
      unsigned long long* dst =
          reinterpret_cast<unsigned long long*>(CD + (size_t)br * NSIDE + C0);
      st_agent_u64(&dst[lane], pack2(s0));        // cols 2l, 2l+1   (coalesced)
      st_agent_u64(&dst[lane + 64], pack2(s1));   // cols 128+2l, ..
      wait_vm0();                                  // slice at coherence point
      if (lane == 0) st_agent_u(&ColFlag[bc * FANIN + br], tag);
    } else if (w <= 4) {
      // waves 1-4: poll 16 flags (replicated over 64 lanes), gather, BF
      const unsigned* fp = &ColFlag[bc * FANIN + (lane & 15)];
      unsigned fv;
      do { fv = ld_agent_u(fp); } while (!__all((int)(fv >= tag)));
      asm volatile("" ::: "memory");               // loads below can't hoist
      const int col = (w - 1) * 64 + lane;
      float tot = 0.f;
#pragma unroll
      for (int ww = 0; ww < 16; ++ww) tot += ld_agent_f(&CD[(size_t)ww * NSIDE + (C0 + col)]);
      BFs[col] = BTs[col] / (1.0f + tot);
    }
    __syncthreads();                                          // B2: BF ready

    // ============ row pass: partial_i = sum_j K_ij * BF_j ============
    {
      const float4 bv0 = *reinterpret_cast<const float4*>(&BFs[c * 8]);
      const float4 bv1 = *reinterpret_cast<const float4*>(&BFs[c * 8 + 4]);
#pragma unroll
      for (int s = 0; s < 8; ++s) {
        const int row = s * 32 + rg;
        const uint4 q = *reinterpret_cast<const uint4*>(&slab[row * SC + c * 8]);
        const float r0 = bfLO(q.x) * bv0.x + bfHI(q.x) * bv0.y;
        const float r1 = bfLO(q.y) * bv0.z + bfHI(q.y) * bv0.w;
        const float r2 = bfLO(q.z) * bv1.x + bfHI(q.z) * bv1.y;
        const float r3 = bfLO(q.w) * bv1.z + bfHI(q.w) * bv1.w;
        float rs = (r0 + r1) + (r2 + r3);
        rs += __shfl_down(rs, 16, 32);
        rs += __shfl_down(rs, 8, 32);
        rs += __shfl_down(rs, 4, 32);
        rs += __shfl_down(rs, 2, 32);
        rs += __shfl_down(rs, 1, 32);
        if (c == 0) rowsum[row] = rs;
      }
    }
    __syncthreads();                                          // B3: rowsum ready

    if (w == 0) {
      f32x2 r0 = *reinterpret_cast<const f32x2*>(&rowsum[2 * lane]);
      f32x2 r1 = *reinterpret_cast<const f32x2*>(&rowsum[128 + 2 * lane]);
      unsigned long long* dst =
          reinterpret_cast<unsigned long long*>(RD + (size_t)bc * NSIDE + R0);
      st_agent_u64(&dst[lane], pack2(r0));
      st_agent_u64(&dst[lane + 64], pack2(r1));
      wait_vm0();
      if (lane == 0) st_agent_u(&RowFlag[br * FANIN + bc], tag);
    } else if (w <= 4) {
      const unsigned* fp = &RowFlag[br * FANIN + (lane & 15)];
      unsigned fv;
      do { fv = ld_agent_u(fp); } while (!__all((int)(fv >= tag)));
      asm volatile("" ::: "memory");
      const int row = (w - 1) * 64 + lane;
      float tot = 0.f;
#pragma unroll
      for (int ww = 0; ww < 16; ++ww) tot += ld_agent_f(&RD[(size_t)ww * NSIDE + (R0 + row)]);
      AFs[row] = ATs[row] / (1.0f + tot);
    }
    __syncthreads();                                          // B4: AF ready
  }

  // ---------------- tail: C_ij = AF_i * (k_ij^2) * BF_j  (fp32 K) ----------------
  {
    const int c4 = t & 63;
    const int rh = t >> 6;
#pragma unroll
    for (int s = 0; s < 16; ++s) {
      const int r = s * 16 + rh;
      const size_t off = (size_t)(R0 + r) * NSIDE + C0;
      const float4 v = reinterpret_cast<const float4*>(kmat + off)[c4];
      const float4 bf = *reinterpret_cast<const float4*>(&BFs[c4 * 4]);
      const float af = AFs[r];
      float4 o;
      o.x = af * (v.x * v.x) * bf.x;
      o.y = af * (v.y * v.y) * bf.y;
      o.z = af * (v.z * v.z) * bf.z;
      o.w = af * (v.w * v.w) * bf.w;
      reinterpret_cast<float4*>(C + off)[c4] = o;
    }
  }
}

extern "C" void kernel_launch(void* const* d_in, const int* in_sizes, int n_in,
                              void* d_out, int out_size, void* d_ws, size_t ws_size,
                              hipStream_t stream) {
  const float* AT = (const float*)d_in[0];
  const float* k  = (const float*)d_in[1];
  const float* bt = (const float*)d_in[2];
  float* C = (float*)d_out;

  unsigned* ColFlag = (unsigned*)d_ws;                       // 256 u32
  unsigned* RowFlag = ColFlag + FANIN * FANIN;               // 256 u32
  float* ColData = (float*)((char*)d_ws + 4096);             // [2][16][4096] f32 = 512 KB
  float* RowData = ColData + (size_t)2 * FANIN * NSIDE;      // [2][16][4096] f32 = 512 KB

  hipLaunchKernelGGL(ws_init_kernel, dim3(1), dim3(512), 0, stream, ColFlag);
  hipLaunchKernelGGL(competitive_kernel, dim3(NBLK), dim3(TPB), 0, stream,
                     AT, k, bt, C, ColFlag, RowFlag, ColData, RowData);
}